// Round 26
// baseline (197.236 us; speedup 1.0000x reference)
//
#include <hip/hip_runtime.h>
#include <hip/hip_bf16.h>

using u16 = unsigned short;
using u32 = unsigned int;

typedef short bf16x8 __attribute__((ext_vector_type(8)));
typedef float f32x4 __attribute__((ext_vector_type(4)));

#define AS1 __attribute__((address_space(1)))
#define AS3 __attribute__((address_space(3)))

__device__ __forceinline__ void gll16(const void* g, void* l) {
  __builtin_amdgcn_global_load_lds((const AS1 u32*)g, (AS3 u32*)l, 16, 0, 0);
}

__device__ __forceinline__ u16 f2bf(float x) {  // round-to-nearest-even bf16
  u32 u = __builtin_bit_cast(u32, x);
  u32 r = (u + 0x7fffu + ((u >> 16) & 1u)) >> 16;
  return (u16)r;
}
__device__ __forceinline__ u32 pk2(float lo, float hi) {
  return (u32)f2bf(lo) | ((u32)f2bf(hi) << 16);
}
__device__ __forceinline__ u16 f2bf_fast(float x) {  // hw cvt (validated r5/r6)
  __hip_bfloat16 h = __float2bfloat16(x);
  return __builtin_bit_cast(u16, h);
}

// ---------------- merged prep: x cast + 4 weight transposes + fused cos/sin table ----------------
__device__ __forceinline__ void trans64(const float* __restrict__ in, u16* __restrict__ out,
                                        int R, int Cc, int bx, int by, float (*tl)[65]) {
  int c0 = bx * 64, r0 = by * 64, tid = threadIdx.x;
#pragma unroll
  for (int i = 0; i < 16; i++) {
    int idx = i * 256 + tid; int tr = idx >> 6, tc = idx & 63;
    tl[tr][tc] = in[(size_t)(r0 + tr) * Cc + c0 + tc];
  }
  __syncthreads();
#pragma unroll
  for (int i = 0; i < 16; i++) {
    int idx = i * 256 + tid; int tr = idx >> 6, tc = idx & 63;
    out[(size_t)(c0 + tr) * R + r0 + tc] = f2bf(tl[tc][tr]);
  }
}

__global__ void k_prep(const float* __restrict__ x, u16* __restrict__ xb,
                       const float* __restrict__ wq, u16* __restrict__ wqt,
                       const float* __restrict__ wk, const float* __restrict__ wv,
                       u16* __restrict__ wkvt,
                       const float* __restrict__ wo, u16* __restrict__ wot,
                       const float* __restrict__ fc, const float* __restrict__ fs,
                       float2* __restrict__ fcs) {
  __shared__ float tl[64][65];
  int gid = blockIdx.x;
  if (gid < 4096) {
    int i = gid * 256 + threadIdx.x;
    const float4* p = (const float4*)(x + (size_t)i * 8);
    float4 a = p[0], b = p[1];
    uint4 o;
    o.x = pk2(a.x, a.y); o.y = pk2(a.z, a.w);
    o.z = pk2(b.x, b.y); o.w = pk2(b.z, b.w);
    *(uint4*)(xb + (size_t)i * 8) = o;
  } else if (gid < 5120) {
    int t = gid - 4096; trans64(wq, wqt, 2048, 2048, t & 31, t >> 5, tl);
  } else if (gid < 5376) {
    int t = gid - 5120; trans64(wk, wkvt, 2048, 512, t & 7, t >> 3, tl);
  } else if (gid < 5632) {
    int t = gid - 5376; trans64(wv, wkvt + 512 * 2048, 2048, 512, t & 7, t >> 3, tl);
  } else if (gid < 6656) {
    int t = gid - 5632; trans64(wo, wot, 2048, 2048, t & 31, t >> 5, tl);
  } else {
    int base = (gid - 6656) * 2048 + threadIdx.x * 8;
#pragma unroll
    for (int j = 0; j < 8; j++) {
      int idx = base + j;
      fcs[idx] = make_float2(fc[idx], fs[idx]);
    }
  }
}

// ---------------- QKV GEMM: heterogeneous tiles (r21-proven) ----------------
__global__ __launch_bounds__(512, 2) void k_gemm_qkv(
    const u16* __restrict__ A, const u16* __restrict__ BT0, const u16* __restrict__ BT1,
    u16* __restrict__ Qout, u16* __restrict__ Kout, u16* __restrict__ Vout,
    const float* __restrict__ nwq, const float* __restrict__ nwk,
    const float2* __restrict__ fcs) {
  __shared__ char lds[147456];
  const int K = 2048;
  int tid = threadIdx.x, w = tid >> 6, l = tid & 63, lg = l >> 4, ll = l & 15;
  int bid = blockIdx.x;

  if (bid < 256) {
    // ---------- HEAVY: Q, BN=256, 3-stage counted-vmcnt ----------
    int wr = w >> 2, wc = w & 3;
    int xcd = bid & 7, r = bid >> 3;
    int colg = xcd & 1, rowg = xcd >> 1;
    int bxt = colg * 4 + (r & 3);
    int bm0 = (rowg * 8 + (r >> 2)) * 128;
    int bn0 = bxt * 256;

    auto stage = [&](int si, int kt) {
      char* Sb = lds + si * 49152;
      int k0 = kt * 64;
#pragma unroll
      for (int i = 0; i < 2; i++) {
        int base = i * 512 + (w << 6);
        int c = base + l;
        int row = c >> 3, kc = (c & 7) ^ (row & 7);
        gll16(A + (size_t)(bm0 + row) * K + k0 + kc * 8, Sb + base * 16);
      }
#pragma unroll
      for (int i = 0; i < 4; i++) {
        int base = i * 512 + (w << 6);
        int c = base + l;
        int row = c >> 3, kc = (c & 7) ^ (row & 7);
        gll16(BT0 + (size_t)(bn0 + row) * K + k0 + kc * 8, Sb + 16384 + base * 16);
      }
    };

    f32x4 acc[4][4] = {};
    stage(0, 0); stage(1, 1);
    asm volatile("s_waitcnt vmcnt(6)" ::: "memory");
    __builtin_amdgcn_s_barrier();
    __builtin_amdgcn_sched_barrier(0);

    for (int kt = 0; kt < 32; ++kt) {
      int cs = kt % 3;
      if (kt + 2 < 32) stage((kt + 2) % 3, kt + 2);
      char* As = lds + cs * 49152;
      char* Bs = As + 16384;
      __builtin_amdgcn_s_setprio(1);
#pragma unroll
      for (int ks = 0; ks < 2; ks++) {
        bf16x8 af[4], bf[4];
#pragma unroll
        for (int m = 0; m < 4; m++) {
          int row = 64 * wr + 16 * m + ll;
          af[m] = *(const bf16x8*)(As + row * 128 + (((lg + 4 * ks) ^ (row & 7)) << 4));
        }
#pragma unroll
        for (int n = 0; n < 4; n++) {
          int row = 64 * wc + 16 * n + ll;
          bf[n] = *(const bf16x8*)(Bs + row * 128 + (((lg + 4 * ks) ^ (row & 7)) << 4));
        }
#pragma unroll
        for (int m = 0; m < 4; m++)
#pragma unroll
          for (int n = 0; n < 4; n++)
            acc[m][n] = __builtin_amdgcn_mfma_f32_16x16x32_bf16(af[m], bf[n], acc[m][n], 0, 0, 0);
      }
      __builtin_amdgcn_s_setprio(0);
      if (kt + 2 < 32) {
        asm volatile("s_waitcnt vmcnt(6)" ::: "memory");
      } else {
        asm volatile("s_waitcnt vmcnt(0)" ::: "memory");
      }
      __builtin_amdgcn_s_barrier();
      __builtin_amdgcn_sched_barrier(0);
    }

    // --- Q epilogue: rmsnorm per 128-col head (wc pairs {0,1},{2,3}) + rope ---
    float* ssum = (float*)lds;
    float ps[4][4];
#pragma unroll
    for (int m = 0; m < 4; m++)
#pragma unroll
      for (int r2 = 0; r2 < 4; r2++) {
        float p = 0.f;
#pragma unroll
        for (int n = 0; n < 4; n++) p += acc[m][n][r2] * acc[m][n][r2];
#pragma unroll
        for (int msk = 1; msk < 16; msk <<= 1) p += __shfl_xor(p, msk);
        ps[m][r2] = p;
      }
    if (ll == 0) {
#pragma unroll
      for (int m = 0; m < 4; m++)
#pragma unroll
        for (int r2 = 0; r2 < 4; r2++)
          ssum[wr * 256 + (16 * m + 4 * lg + r2) * 4 + wc] = ps[m][r2];
    }
    __syncthreads();
    int pbase = (wc < 2) ? 0 : 2;
    float rs[4][4];
#pragma unroll
    for (int m = 0; m < 4; m++)
#pragma unroll
      for (int r2 = 0; r2 < 4; r2++) {
        int rowl = 16 * m + 4 * lg + r2;
        const float* sp = ssum + wr * 256 + rowl * 4;
        float tot = sp[pbase] + sp[pbase + 1];
        rs[m][r2] = rsqrtf(tot * (1.0f / 128.0f) + 1e-5f) * 0.12751744843f;
      }
#pragma unroll
    for (int m = 0; m < 4; m++)
#pragma unroll
      for (int n = 0; n < 4; n++) {
        int col = bn0 + 64 * wc + 16 * n + ll;
        int d = col & 127;
        float wgt = nwq[d];
        int i = d >> 1;
#pragma unroll
        for (int r2 = 0; r2 < 4; r2++) {
          int row = bm0 + 64 * wr + 16 * m + 4 * lg + r2;
          int t = row & 2047;
          float y = acc[m][n][r2] * rs[m][r2] * wgt;
          float p = __shfl_xor(y, 1);
          float2 cs2 = fcs[t * 64 + i];
          float o = (ll & 1) ? (p * cs2.y + y * cs2.x) : (y * cs2.x - p * cs2.y);
          Qout[(size_t)row * 2048 + col] = f2bf(o);
        }
      }
  } else {
    // ---------- LIGHT: K/V, BN=128, 4-stage counted-vmcnt ----------
    int wr = w >> 2, wc = w & 3;
    int lid = bid - 256;
    int xcd = lid & 7, r = lid >> 3;
    int colg = xcd & 1, rowg = xcd >> 1;
    int bxt = colg * 4 + (r & 3);
    int bm0 = (rowg * 8 + (r >> 2)) * 128;
    int bn0 = bxt * 128;
    bool kpath = (bn0 < 512);

    auto stage = [&](int si, int kt) {
      char* Sb = lds + si * 32768;
      int k0 = kt * 64;
#pragma unroll
      for (int i = 0; i < 2; i++) {
        int base = i * 512 + (w << 6);
        int c = base + l;
        int row = c >> 3, kc = (c & 7) ^ (row & 7);
        gll16(A + (size_t)(bm0 + row) * K + k0 + kc * 8, Sb + base * 16);
        gll16(BT1 + (size_t)(bn0 + row) * K + k0 + kc * 8, Sb + 16384 + base * 16);
      }
    };

    f32x4 acc[4][2] = {};
    stage(0, 0); stage(1, 1); stage(2, 2);
    asm volatile("s_waitcnt vmcnt(8)" ::: "memory");
    __builtin_amdgcn_s_barrier();
    __builtin_amdgcn_sched_barrier(0);

    for (int kt = 0; kt < 32; ++kt) {
      int cs = kt & 3;
      if (kt + 3 < 32) stage((kt + 3) & 3, kt + 3);
      char* As = lds + cs * 32768;
      char* Bs = As + 16384;
      __builtin_amdgcn_s_setprio(1);
#pragma unroll
      for (int ks = 0; ks < 2; ks++) {
        bf16x8 af[4], bf[2];
#pragma unroll
        for (int m = 0; m < 4; m++) {
          int row = 64 * wr + 16 * m + ll;
          af[m] = *(const bf16x8*)(As + row * 128 + (((lg + 4 * ks) ^ (row & 7)) << 4));
        }
#pragma unroll
        for (int n = 0; n < 2; n++) {
          int row = 32 * wc + 16 * n + ll;
          bf[n] = *(const bf16x8*)(Bs + row * 128 + (((lg + 4 * ks) ^ (row & 7)) << 4));
        }
#pragma unroll
        for (int m = 0; m < 4; m++)
#pragma unroll
          for (int n = 0; n < 2; n++)
            acc[m][n] = __builtin_amdgcn_mfma_f32_16x16x32_bf16(af[m], bf[n], acc[m][n], 0, 0, 0);
      }
      __builtin_amdgcn_s_setprio(0);
      if (kt <= 28) {
        asm volatile("s_waitcnt vmcnt(8)" ::: "memory");
      } else if (kt == 29) {
        asm volatile("s_waitcnt vmcnt(4)" ::: "memory");
      } else {
        asm volatile("s_waitcnt vmcnt(0)" ::: "memory");
      }
      __builtin_amdgcn_s_barrier();
      __builtin_amdgcn_sched_barrier(0);
    }

    if (kpath) {
      float* ssum = (float*)lds;
      float ps[4][4];
#pragma unroll
      for (int m = 0; m < 4; m++)
#pragma unroll
        for (int r2 = 0; r2 < 4; r2++) {
          float p = 0.f;
#pragma unroll
          for (int n = 0; n < 2; n++) p += acc[m][n][r2] * acc[m][n][r2];
#pragma unroll
          for (int msk = 1; msk < 16; msk <<= 1) p += __shfl_xor(p, msk);
          ps[m][r2] = p;
        }
      if (ll == 0) {
#pragma unroll
        for (int m = 0; m < 4; m++)
#pragma unroll
          for (int r2 = 0; r2 < 4; r2++)
            ssum[wr * 256 + (16 * m + 4 * lg + r2) * 4 + wc] = ps[m][r2];
      }
      __syncthreads();
      float rs[4][4];
#pragma unroll
      for (int m = 0; m < 4; m++)
#pragma unroll
        for (int r2 = 0; r2 < 4; r2++) {
          int rowl = 16 * m + 4 * lg + r2;
          const float* sp = ssum + wr * 256 + rowl * 4;
          float tot = sp[0] + sp[1] + sp[2] + sp[3];
          rs[m][r2] = rsqrtf(tot * (1.0f / 128.0f) + 1e-5f);
        }
#pragma unroll
      for (int m = 0; m < 4; m++)
#pragma unroll
        for (int n = 0; n < 2; n++) {
          int col = bn0 + 32 * wc + 16 * n + ll;
          int d = col & 127;
          float wgt = nwk[d];
          int i = d >> 1;
#pragma unroll
          for (int r2 = 0; r2 < 4; r2++) {
            int row = bm0 + 64 * wr + 16 * m + 4 * lg + r2;
            int t = row & 2047;
            float y = acc[m][n][r2] * rs[m][r2] * wgt;
            float p = __shfl_xor(y, 1);
            float2 cs2 = fcs[t * 64 + i];
            float o = (ll & 1) ? (p * cs2.y + y * cs2.x) : (y * cs2.x - p * cs2.y);
            Kout[(size_t)row * 512 + col] = f2bf(o);
          }
        }
    } else {
      int b = bm0 >> 11, t0g = bm0 & 2047;
      int kvh = (bn0 - 512) >> 7;
      int bk = b * 4 + kvh;
#pragma unroll
      for (int m = 0; m < 4; m++)
#pragma unroll
        for (int n = 0; n < 2; n++) {
          int d = 32 * wc + 16 * n + ll;
          int tloc = 64 * wr + 16 * m + 4 * lg;
          u32 w0 = pk2(acc[m][n][0], acc[m][n][1]);
          u32 w1 = pk2(acc[m][n][2], acc[m][n][3]);
          int byte = (d * 256 + tloc * 2) ^ ((d & 7) << 4);
          *(uint2*)(lds + byte) = make_uint2(w0, w1);
        }
      __syncthreads();
      int tc = tid & 15, dbase = tid >> 4;
#pragma unroll
      for (int pass = 0; pass < 4; pass++) {
        int d = dbase + pass * 32;
        int byte = (d * 256 + tc * 16) ^ ((d & 7) << 4);
        uint4 v = *(const uint4*)(lds + byte);
        *(uint4*)(Vout + ((size_t)(bk * 128 + d)) * 2048 + t0g + tc * 8) = v;
      }
    }
  }
}

// ---------------- O-projection GEMM: 128x256 tile, 3-stage counted-vmcnt (r20-proven) ----------------
__global__ __launch_bounds__(512, 2) void k_gemm_o(
    const u16* __restrict__ A, const u16* __restrict__ BT, float* __restrict__ C) {
  __shared__ char lds[147456];
  const int K = 2048;
  int tid = threadIdx.x, w = tid >> 6, l = tid & 63, lg = l >> 4, ll = l & 15;
  int wr = w >> 2, wc = w & 3;
  int lid = blockIdx.y * 8 + blockIdx.x;
  int xcd = lid & 7, r = lid >> 3;
  int colg = xcd & 1, rowg = xcd >> 1;
  int bxt = colg * 4 + (r & 3);
  int bm0 = (rowg * 8 + (r >> 2)) * 128;
  int bn0 = bxt * 256;

  auto stage = [&](int si, int kt) {
    char* Sb = lds + si * 49152;
    int k0 = kt * 64;
#pragma unroll
    for (int i = 0; i < 2; i++) {
      int base = i * 512 + (w << 6);
      int c = base + l;
      int row = c >> 3, kc = (c & 7) ^ (row & 7);
      gll16(A + (size_t)(bm0 + row) * K + k0 + kc * 8, Sb + base * 16);
    }
#pragma unroll
    for (int i = 0; i < 4; i++) {
      int base = i * 512 + (w << 6);
      int c = base + l;
      int row = c >> 3, kc = (c & 7) ^ (row & 7);
      gll16(BT + (size_t)(bn0 + row) * K + k0 + kc * 8, Sb + 16384 + base * 16);
    }
  };

  f32x4 acc[4][4] = {};
  stage(0, 0); stage(1, 1);
  asm volatile("s_waitcnt vmcnt(6)" ::: "memory");
  __builtin_amdgcn_s_barrier();
  __builtin_amdgcn_sched_barrier(0);

  for (int kt = 0; kt < 32; ++kt) {
    int cs = kt % 3;
    if (kt + 2 < 32) stage((kt + 2) % 3, kt + 2);
    char* As = lds + cs * 49152;
    char* Bs = As + 16384;
    __builtin_amdgcn_s_setprio(1);
#pragma unroll
    for (int ks = 0; ks < 2; ks++) {
      bf16x8 af[4], bf[4];
#pragma unroll
      for (int m = 0; m < 4; m++) {
        int row = 64 * wr + 16 * m + ll;
        af[m] = *(const bf16x8*)(As + row * 128 + (((lg + 4 * ks) ^ (row & 7)) << 4));
      }
#pragma unroll
      for (int n = 0; n < 4; n++) {
        int row = 64 * wc + 16 * n + ll;
        bf[n] = *(const bf16x8*)(Bs + row * 128 + (((lg + 4 * ks) ^ (row & 7)) << 4));
      }
#pragma unroll
      for (int m = 0; m < 4; m++)
#pragma unroll
        for (int n = 0; n < 4; n++)
          acc[m][n] = __builtin_amdgcn_mfma_f32_16x16x32_bf16(af[m], bf[n], acc[m][n], 0, 0, 0);
    }
    __builtin_amdgcn_s_setprio(0);
    if (kt + 2 < 32) {
      asm volatile("s_waitcnt vmcnt(6)" ::: "memory");
    } else {
      asm volatile("s_waitcnt vmcnt(0)" ::: "memory");
    }
    __builtin_amdgcn_s_barrier();
    __builtin_amdgcn_sched_barrier(0);
  }

#pragma unroll
  for (int m = 0; m < 4; m++)
#pragma unroll
    for (int n = 0; n < 4; n++) {
      int row = bm0 + 64 * wr + 16 * m + 4 * lg;
      int col = bn0 + 64 * wc + 16 * n + ll;
      float* cp = C + (size_t)row * 2048 + col;
#pragma unroll
      for (int r2 = 0; r2 < 4; r2++) cp[(size_t)r2 * 2048] = acc[m][n][r2];
    }
}

// ---------------- causal GQA flash attention: 32 q-rows/wave + WITHIN-BLOCK pairing (r26) ----------------
// r24 amplification fix (each kf/vf feeds 2 MFMAs) + r19-style sequential pairing:
// every block runs q-tiles {v, 31-v} itself -> EVERY block = 33 tile-iters (uniform),
// both co-resident blocks alive to the end (r25 lesson: co-resident complementary
// blocks don't balance -- the light one exits early and the heavy tail runs alone).
// 256 blocks (2/CU): fid&7 -> (b,kvh) XCD slice; hp=(fid>>3)&1; v=(fid>>4)&15.
// Block = 2 heads x 64 q-rows (4 waves: head=w&1, rgrp=w>>1). LDS 72KB -> 2 blocks/CU.
__global__ __launch_bounds__(256, 2) void k_attn(
    const u16* __restrict__ Q, const u16* __restrict__ Kb,
    const u16* __restrict__ Vt, u16* __restrict__ Y) {
  __shared__ char lds[73728];  // K0 16K | V0 16K | K1 16K | V1 16K | P 8K
  char* Ps = lds + 65536;
  int tid = threadIdx.x, w = tid >> 6, l = tid & 63, lg = l >> 4, ll = l & 15;
  int fid = blockIdx.x;
  int g = fid & 7;                    // (b,kvh) -> XCD-local K/V slice
  int b = g >> 2, kvh = g & 3;
  int hp = (fid >> 3) & 1;            // head pair within kvh
  int v = (fid >> 4) & 15;
  int h = kvh * 4 + hp * 2 + (w & 1); // head per wave
  int rgrp = w >> 1;                  // 0..1: 32-row group within the 64-row tile
  const u16* Kbase = Kb + ((size_t)b * 2048) * 512 + kvh * 128;
  const u16* Vbase = Vt + ((size_t)(b * 4 + kvh) * 128) * 2048;

  const bf16x8 vones = {(short)0x3F80, (short)0x3F80, (short)0x3F80, (short)0x3F80,
                        (short)0x3F80, (short)0x3F80, (short)0x3F80, (short)0x3F80};

  auto stage = [&](int bi, int k0) {
    char* Kd = lds + (bi ? 32768 : 0);
    char* Vd = Kd + 16384;
#pragma unroll
    for (int i = 0; i < 4; i++) {   // 256 thr: 4 chunks each per buffer
      int base = i * 256 + (w << 6);
      int c = base + l;
      int dst = base * 16;
      int krow = c >> 4, ksrc = (c & 15) ^ (krow & 7);   // K tile [64][128]
      gll16(Kbase + (size_t)(k0 + krow) * 512 + ksrc * 8, Kd + dst);
      int vd = c >> 3, vsrc = (c & 7) ^ (vd & 7);        // V tile [128][64]
      gll16(Vbase + (size_t)vd * 2048 + k0 + vsrc * 8, Vd + dst);
    }
  };

#pragma unroll 1
  for (int qi = 0; qi < 2; qi++) {
    int qt = qi ? (31 - v) : v;       // within-block pairing: total 33 tiles/block
    int q0 = qt * 64;
    int nt = qt + 1;                  // KV tiles of 64 covering [0, q0+64)

    // Q fragments: 32 rows = 2 m-groups of 16
    bf16x8 qf[2][4];
#pragma unroll
    for (int m = 0; m < 2; m++) {
      int qrow = b * 2048 + q0 + rgrp * 32 + m * 16 + ll;
      const u16* qp = Q + (size_t)qrow * 2048 + h * 128;
#pragma unroll
      for (int ks = 0; ks < 4; ks++) qf[m][ks] = *(const bf16x8*)(qp + ks * 32 + lg * 8);
    }
    f32x4 o[2][8] = {};
    f32x4 lacc[2] = {};

    stage(0, 0);
    asm volatile("s_waitcnt vmcnt(0)" ::: "memory");
    __syncthreads();

    int cur = 0;
    for (int it = 0; it < nt; ++it) {
      if (it + 1 < nt) stage(cur ^ 1, (it + 1) * 64);
      char* Ks = lds + (cur ? 32768 : 0);
      char* Vs = Ks + 16384;
      // S = Q K^T: each kf feeds both m-groups (the amplification fix)
      f32x4 s[2][4] = {};
      __builtin_amdgcn_s_setprio(1);
#pragma unroll
      for (int ks = 0; ks < 4; ks++) {
#pragma unroll
        for (int n = 0; n < 4; n++) {
          int row = 16 * n + ll;
          bf16x8 kf = *(const bf16x8*)(Ks + ((row * 256 + (lg + 4 * ks) * 16) ^ ((row & 7) << 4)));
          s[0][n] = __builtin_amdgcn_mfma_f32_16x16x32_bf16(qf[0][ks], kf, s[0][n], 0, 0, 0);
          s[1][n] = __builtin_amdgcn_mfma_f32_16x16x32_bf16(qf[1][ks], kf, s[1][n], 0, 0, 0);
        }
      }
      __builtin_amdgcn_s_setprio(0);
      if (it == nt - 1) {  // diagonal tile: causal mask
        int k0 = it * 64;
#pragma unroll
        for (int m = 0; m < 2; m++)
#pragma unroll
          for (int n = 0; n < 4; n++) {
            int kk = k0 + 16 * n + ll;
#pragma unroll
            for (int r = 0; r < 4; r++) {
              int qq = q0 + rgrp * 32 + m * 16 + 4 * lg + r;
              if (kk > qq) s[m][n][r] = -1e30f;
            }
          }
      }
      // Per kv-half hs: write P[32 rows][32 kv] half (wave-local), then PV on that half.
#pragma unroll
      for (int hs = 0; hs < 2; hs++) {
#pragma unroll
        for (int m = 0; m < 2; m++)
#pragma unroll
          for (int r = 0; r < 4; r++) {
            int prow = m * 16 + 4 * lg + r;
            int swz = ((prow >> 2) & 3) << 4;
#pragma unroll
            for (int nn = 0; nn < 2; nn++) {
              int n = 2 * hs + nn;
              float e = exp2f(s[m][n][r]);   // static-normalizer softmax
              int lcol = 16 * nn + ll;
              int byte = (w << 11) + ((prow * 64 + lcol * 2) ^ swz);
              *(u16*)(Ps + byte) = f2bf_fast(e);
            }
          }
        // O += P V ; l += P 1  (pf per m; vf shared across m)
        __builtin_amdgcn_s_setprio(1);
        bf16x8 pfm[2];
#pragma unroll
        for (int m = 0; m < 2; m++) {
          int prow = m * 16 + ll;
          pfm[m] = *(const bf16x8*)(Ps + (w << 11) + ((prow * 64 + lg * 16) ^ (((prow >> 2) & 3) << 4)));
          lacc[m] = __builtin_amdgcn_mfma_f32_16x16x32_bf16(pfm[m], vones, lacc[m], 0, 0, 0);
        }
#pragma unroll
        for (int n = 0; n < 8; n++) {
          int row = 16 * n + ll;
          bf16x8 vf = *(const bf16x8*)(Vs + ((row * 128 + (lg + 4 * hs) * 16) ^ ((row & 7) << 4)));
          o[0][n] = __builtin_amdgcn_mfma_f32_16x16x32_bf16(pfm[0], vf, o[0][n], 0, 0, 0);
          o[1][n] = __builtin_amdgcn_mfma_f32_16x16x32_bf16(pfm[1], vf, o[1][n], 0, 0, 0);
        }
        __builtin_amdgcn_s_setprio(0);
      }
      // drain this iteration's prefetch, publish to all waves
      asm volatile("s_waitcnt vmcnt(0)" ::: "memory");
      __syncthreads();
      cur ^= 1;
    }
    // output
#pragma unroll
    for (int m = 0; m < 2; m++) {
      float rl[4];
#pragma unroll
      for (int r = 0; r < 4; r++) rl[r] = 1.0f / lacc[m][r];
#pragma unroll
      for (int n = 0; n < 8; n++) {
        int col = h * 128 + 16 * n + ll;
#pragma unroll
        for (int r = 0; r < 4; r++) {
          int trow = b * 2048 + q0 + rgrp * 32 + m * 16 + 4 * lg + r;
          Y[(size_t)trow * 2048 + col] = f2bf_fast(o[m][n][r] * rl[r]);
        }
      }
    }
  }
}

extern "C" void kernel_launch(void* const* d_in, const int* in_sizes, int n_in,
                              void* d_out, int out_size, void* d_ws, size_t ws_size,
                              hipStream_t stream) {
  const float* x   = (const float*)d_in[0];
  const float* fc  = (const float*)d_in[1];
  const float* fs  = (const float*)d_in[2];
  const float* wq  = (const float*)d_in[3];
  const float* wk  = (const float*)d_in[4];
  const float* wv  = (const float*)d_in[5];
  const float* wo  = (const float*)d_in[6];
  const float* qnw = (const float*)d_in[7];
  const float* knw = (const float*)d_in[8];
  float* out = (float*)d_out;

  const size_t MB = 1ull << 20;
  char* ws = (char*)d_ws;
  u16*    xb   = (u16*)(ws);             // 16 MB  x bf16
  u16*    wqt  = (u16*)(ws + 16 * MB);   //  8 MB  wq^T bf16 [2048][2048]
  u16*    wkvt = (u16*)(ws + 24 * MB);   //  4 MB  [wk^T;wv^T] bf16 [1024][2048]
  u16*    wot  = (u16*)(ws + 28 * MB);   //  8 MB  wo^T bf16
  u16*    Qb   = (u16*)(ws + 36 * MB);   // 16 MB  Q' bf16 (rms+rope, x log2e/sqrt(D))
  u16*    Kbq  = (u16*)(ws + 52 * MB);   //  4 MB  K' bf16 (rms+rope)
  u16*    Vtg  = (u16*)(ws + 56 * MB);   //  4 MB  V^T bf16 (b,kvh,d,t)
  u16*    Yb   = (u16*)(ws + 60 * MB);   // 16 MB  attn out bf16
  float2* fcs  = (float2*)(ws + 76 * MB);//  1 MB  fused (cos,sin) table

  hipLaunchKernelGGL(k_prep, dim3(6720), dim3(256), 0, stream,
                     x, xb, wq, wqt, wk, wv, wkvt, wo, wot, fc, fs, fcs);
  hipLaunchKernelGGL(k_gemm_qkv, dim3(512), dim3(512), 0, stream,
                     xb, wqt, wkvt, Qb, Kbq, Vtg, qnw, knw, fcs);
  hipLaunchKernelGGL(k_attn, dim3(256), dim3(256), 0, stream, Qb, Kbq, Vtg, Yb);
  hipLaunchKernelGGL(k_gemm_o, dim3(8, 32), dim3(512), 0, stream, Yb, wot, out);
}

// Round 27
// 186.667 us; speedup vs baseline: 1.0566x; 1.0566x over previous
//
#include <hip/hip_runtime.h>
#include <hip/hip_bf16.h>

using u16 = unsigned short;
using u32 = unsigned int;

typedef short bf16x8 __attribute__((ext_vector_type(8)));
typedef float f32x4 __attribute__((ext_vector_type(4)));

#define AS1 __attribute__((address_space(1)))
#define AS3 __attribute__((address_space(3)))

__device__ __forceinline__ void gll16(const void* g, void* l) {
  __builtin_amdgcn_global_load_lds((const AS1 u32*)g, (AS3 u32*)l, 16, 0, 0);
}

__device__ __forceinline__ u16 f2bf(float x) {  // round-to-nearest-even bf16
  u32 u = __builtin_bit_cast(u32, x);
  u32 r = (u + 0x7fffu + ((u >> 16) & 1u)) >> 16;
  return (u16)r;
}
__device__ __forceinline__ u32 pk2(float lo, float hi) {
  return (u32)f2bf(lo) | ((u32)f2bf(hi) << 16);
}
__device__ __forceinline__ u16 f2bf_fast(float x) {  // hw cvt (validated r5/r6)
  __hip_bfloat16 h = __float2bfloat16(x);
  return __builtin_bit_cast(u16, h);
}

// ---------------- merged prep: x cast + 4 weight transposes + fused cos/sin table ----------------
__device__ __forceinline__ void trans64(const float* __restrict__ in, u16* __restrict__ out,
                                        int R, int Cc, int bx, int by, float (*tl)[65]) {
  int c0 = bx * 64, r0 = by * 64, tid = threadIdx.x;
#pragma unroll
  for (int i = 0; i < 16; i++) {
    int idx = i * 256 + tid; int tr = idx >> 6, tc = idx & 63;
    tl[tr][tc] = in[(size_t)(r0 + tr) * Cc + c0 + tc];
  }
  __syncthreads();
#pragma unroll
  for (int i = 0; i < 16; i++) {
    int idx = i * 256 + tid; int tr = idx >> 6, tc = idx & 63;
    out[(size_t)(c0 + tr) * R + r0 + tc] = f2bf(tl[tc][tr]);
  }
}

__global__ void k_prep(const float* __restrict__ x, u16* __restrict__ xb,
                       const float* __restrict__ wq, u16* __restrict__ wqt,
                       const float* __restrict__ wk, const float* __restrict__ wv,
                       u16* __restrict__ wkvt,
                       const float* __restrict__ wo, u16* __restrict__ wot,
                       const float* __restrict__ fc, const float* __restrict__ fs,
                       float2* __restrict__ fcs) {
  __shared__ float tl[64][65];
  int gid = blockIdx.x;
  if (gid < 4096) {
    int i = gid * 256 + threadIdx.x;
    const float4* p = (const float4*)(x + (size_t)i * 8);
    float4 a = p[0], b = p[1];
    uint4 o;
    o.x = pk2(a.x, a.y); o.y = pk2(a.z, a.w);
    o.z = pk2(b.x, b.y); o.w = pk2(b.z, b.w);
    *(uint4*)(xb + (size_t)i * 8) = o;
  } else if (gid < 5120) {
    int t = gid - 4096; trans64(wq, wqt, 2048, 2048, t & 31, t >> 5, tl);
  } else if (gid < 5376) {
    int t = gid - 5120; trans64(wk, wkvt, 2048, 512, t & 7, t >> 3, tl);
  } else if (gid < 5632) {
    int t = gid - 5376; trans64(wv, wkvt + 512 * 2048, 2048, 512, t & 7, t >> 3, tl);
  } else if (gid < 6656) {
    int t = gid - 5632; trans64(wo, wot, 2048, 2048, t & 31, t >> 5, tl);
  } else {
    int base = (gid - 6656) * 2048 + threadIdx.x * 8;
#pragma unroll
    for (int j = 0; j < 8; j++) {
      int idx = base + j;
      fcs[idx] = make_float2(fc[idx], fs[idx]);
    }
  }
}

// ---------------- QKV GEMM: heterogeneous tiles (r21-proven) ----------------
__global__ __launch_bounds__(512, 2) void k_gemm_qkv(
    const u16* __restrict__ A, const u16* __restrict__ BT0, const u16* __restrict__ BT1,
    u16* __restrict__ Qout, u16* __restrict__ Kout, u16* __restrict__ Vout,
    const float* __restrict__ nwq, const float* __restrict__ nwk,
    const float2* __restrict__ fcs) {
  __shared__ char lds[147456];
  const int K = 2048;
  int tid = threadIdx.x, w = tid >> 6, l = tid & 63, lg = l >> 4, ll = l & 15;
  int bid = blockIdx.x;

  if (bid < 256) {
    // ---------- HEAVY: Q, BN=256, 3-stage counted-vmcnt ----------
    int wr = w >> 2, wc = w & 3;
    int xcd = bid & 7, r = bid >> 3;
    int colg = xcd & 1, rowg = xcd >> 1;
    int bxt = colg * 4 + (r & 3);
    int bm0 = (rowg * 8 + (r >> 2)) * 128;
    int bn0 = bxt * 256;

    auto stage = [&](int si, int kt) {
      char* Sb = lds + si * 49152;
      int k0 = kt * 64;
#pragma unroll
      for (int i = 0; i < 2; i++) {
        int base = i * 512 + (w << 6);
        int c = base + l;
        int row = c >> 3, kc = (c & 7) ^ (row & 7);
        gll16(A + (size_t)(bm0 + row) * K + k0 + kc * 8, Sb + base * 16);
      }
#pragma unroll
      for (int i = 0; i < 4; i++) {
        int base = i * 512 + (w << 6);
        int c = base + l;
        int row = c >> 3, kc = (c & 7) ^ (row & 7);
        gll16(BT0 + (size_t)(bn0 + row) * K + k0 + kc * 8, Sb + 16384 + base * 16);
      }
    };

    f32x4 acc[4][4] = {};
    stage(0, 0); stage(1, 1);
    asm volatile("s_waitcnt vmcnt(6)" ::: "memory");
    __builtin_amdgcn_s_barrier();
    __builtin_amdgcn_sched_barrier(0);

    for (int kt = 0; kt < 32; ++kt) {
      int cs = kt % 3;
      if (kt + 2 < 32) stage((kt + 2) % 3, kt + 2);
      char* As = lds + cs * 49152;
      char* Bs = As + 16384;
      __builtin_amdgcn_s_setprio(1);
#pragma unroll
      for (int ks = 0; ks < 2; ks++) {
        bf16x8 af[4], bf[4];
#pragma unroll
        for (int m = 0; m < 4; m++) {
          int row = 64 * wr + 16 * m + ll;
          af[m] = *(const bf16x8*)(As + row * 128 + (((lg + 4 * ks) ^ (row & 7)) << 4));
        }
#pragma unroll
        for (int n = 0; n < 4; n++) {
          int row = 64 * wc + 16 * n + ll;
          bf[n] = *(const bf16x8*)(Bs + row * 128 + (((lg + 4 * ks) ^ (row & 7)) << 4));
        }
#pragma unroll
        for (int m = 0; m < 4; m++)
#pragma unroll
          for (int n = 0; n < 4; n++)
            acc[m][n] = __builtin_amdgcn_mfma_f32_16x16x32_bf16(af[m], bf[n], acc[m][n], 0, 0, 0);
      }
      __builtin_amdgcn_s_setprio(0);
      if (kt + 2 < 32) {
        asm volatile("s_waitcnt vmcnt(6)" ::: "memory");
      } else {
        asm volatile("s_waitcnt vmcnt(0)" ::: "memory");
      }
      __builtin_amdgcn_s_barrier();
      __builtin_amdgcn_sched_barrier(0);
    }

    // --- Q epilogue: rmsnorm per 128-col head (wc pairs {0,1},{2,3}) + rope ---
    float* ssum = (float*)lds;
    float ps[4][4];
#pragma unroll
    for (int m = 0; m < 4; m++)
#pragma unroll
      for (int r2 = 0; r2 < 4; r2++) {
        float p = 0.f;
#pragma unroll
        for (int n = 0; n < 4; n++) p += acc[m][n][r2] * acc[m][n][r2];
#pragma unroll
        for (int msk = 1; msk < 16; msk <<= 1) p += __shfl_xor(p, msk);
        ps[m][r2] = p;
      }
    if (ll == 0) {
#pragma unroll
      for (int m = 0; m < 4; m++)
#pragma unroll
        for (int r2 = 0; r2 < 4; r2++)
          ssum[wr * 256 + (16 * m + 4 * lg + r2) * 4 + wc] = ps[m][r2];
    }
    __syncthreads();
    int pbase = (wc < 2) ? 0 : 2;
    float rs[4][4];
#pragma unroll
    for (int m = 0; m < 4; m++)
#pragma unroll
      for (int r2 = 0; r2 < 4; r2++) {
        int rowl = 16 * m + 4 * lg + r2;
        const float* sp = ssum + wr * 256 + rowl * 4;
        float tot = sp[pbase] + sp[pbase + 1];
        rs[m][r2] = rsqrtf(tot * (1.0f / 128.0f) + 1e-5f) * 0.12751744843f;
      }
#pragma unroll
    for (int m = 0; m < 4; m++)
#pragma unroll
      for (int n = 0; n < 4; n++) {
        int col = bn0 + 64 * wc + 16 * n + ll;
        int d = col & 127;
        float wgt = nwq[d];
        int i = d >> 1;
#pragma unroll
        for (int r2 = 0; r2 < 4; r2++) {
          int row = bm0 + 64 * wr + 16 * m + 4 * lg + r2;
          int t = row & 2047;
          float y = acc[m][n][r2] * rs[m][r2] * wgt;
          float p = __shfl_xor(y, 1);
          float2 cs2 = fcs[t * 64 + i];
          float o = (ll & 1) ? (p * cs2.y + y * cs2.x) : (y * cs2.x - p * cs2.y);
          Qout[(size_t)row * 2048 + col] = f2bf(o);
        }
      }
  } else {
    // ---------- LIGHT: K/V, BN=128, 4-stage counted-vmcnt ----------
    int wr = w >> 2, wc = w & 3;
    int lid = bid - 256;
    int xcd = lid & 7, r = lid >> 3;
    int colg = xcd & 1, rowg = xcd >> 1;
    int bxt = colg * 4 + (r & 3);
    int bm0 = (rowg * 8 + (r >> 2)) * 128;
    int bn0 = bxt * 128;
    bool kpath = (bn0 < 512);

    auto stage = [&](int si, int kt) {
      char* Sb = lds + si * 32768;
      int k0 = kt * 64;
#pragma unroll
      for (int i = 0; i < 2; i++) {
        int base = i * 512 + (w << 6);
        int c = base + l;
        int row = c >> 3, kc = (c & 7) ^ (row & 7);
        gll16(A + (size_t)(bm0 + row) * K + k0 + kc * 8, Sb + base * 16);
        gll16(BT1 + (size_t)(bn0 + row) * K + k0 + kc * 8, Sb + 16384 + base * 16);
      }
    };

    f32x4 acc[4][2] = {};
    stage(0, 0); stage(1, 1); stage(2, 2);
    asm volatile("s_waitcnt vmcnt(8)" ::: "memory");
    __builtin_amdgcn_s_barrier();
    __builtin_amdgcn_sched_barrier(0);

    for (int kt = 0; kt < 32; ++kt) {
      int cs = kt & 3;
      if (kt + 3 < 32) stage((kt + 3) & 3, kt + 3);
      char* As = lds + cs * 32768;
      char* Bs = As + 16384;
      __builtin_amdgcn_s_setprio(1);
#pragma unroll
      for (int ks = 0; ks < 2; ks++) {
        bf16x8 af[4], bf[2];
#pragma unroll
        for (int m = 0; m < 4; m++) {
          int row = 64 * wr + 16 * m + ll;
          af[m] = *(const bf16x8*)(As + row * 128 + (((lg + 4 * ks) ^ (row & 7)) << 4));
        }
#pragma unroll
        for (int n = 0; n < 2; n++) {
          int row = 32 * wc + 16 * n + ll;
          bf[n] = *(const bf16x8*)(Bs + row * 128 + (((lg + 4 * ks) ^ (row & 7)) << 4));
        }
#pragma unroll
        for (int m = 0; m < 4; m++)
#pragma unroll
          for (int n = 0; n < 2; n++)
            acc[m][n] = __builtin_amdgcn_mfma_f32_16x16x32_bf16(af[m], bf[n], acc[m][n], 0, 0, 0);
      }
      __builtin_amdgcn_s_setprio(0);
      if (kt <= 28) {
        asm volatile("s_waitcnt vmcnt(8)" ::: "memory");
      } else if (kt == 29) {
        asm volatile("s_waitcnt vmcnt(4)" ::: "memory");
      } else {
        asm volatile("s_waitcnt vmcnt(0)" ::: "memory");
      }
      __builtin_amdgcn_s_barrier();
      __builtin_amdgcn_sched_barrier(0);
    }

    if (kpath) {
      float* ssum = (float*)lds;
      float ps[4][4];
#pragma unroll
      for (int m = 0; m < 4; m++)
#pragma unroll
        for (int r2 = 0; r2 < 4; r2++) {
          float p = 0.f;
#pragma unroll
          for (int n = 0; n < 2; n++) p += acc[m][n][r2] * acc[m][n][r2];
#pragma unroll
          for (int msk = 1; msk < 16; msk <<= 1) p += __shfl_xor(p, msk);
          ps[m][r2] = p;
        }
      if (ll == 0) {
#pragma unroll
        for (int m = 0; m < 4; m++)
#pragma unroll
          for (int r2 = 0; r2 < 4; r2++)
            ssum[wr * 256 + (16 * m + 4 * lg + r2) * 4 + wc] = ps[m][r2];
      }
      __syncthreads();
      float rs[4][4];
#pragma unroll
      for (int m = 0; m < 4; m++)
#pragma unroll
        for (int r2 = 0; r2 < 4; r2++) {
          int rowl = 16 * m + 4 * lg + r2;
          const float* sp = ssum + wr * 256 + rowl * 4;
          float tot = sp[0] + sp[1] + sp[2] + sp[3];
          rs[m][r2] = rsqrtf(tot * (1.0f / 128.0f) + 1e-5f);
        }
#pragma unroll
      for (int m = 0; m < 4; m++)
#pragma unroll
        for (int n = 0; n < 2; n++) {
          int col = bn0 + 32 * wc + 16 * n + ll;
          int d = col & 127;
          float wgt = nwk[d];
          int i = d >> 1;
#pragma unroll
          for (int r2 = 0; r2 < 4; r2++) {
            int row = bm0 + 64 * wr + 16 * m + 4 * lg + r2;
            int t = row & 2047;
            float y = acc[m][n][r2] * rs[m][r2] * wgt;
            float p = __shfl_xor(y, 1);
            float2 cs2 = fcs[t * 64 + i];
            float o = (ll & 1) ? (p * cs2.y + y * cs2.x) : (y * cs2.x - p * cs2.y);
            Kout[(size_t)row * 512 + col] = f2bf(o);
          }
        }
    } else {
      int b = bm0 >> 11, t0g = bm0 & 2047;
      int kvh = (bn0 - 512) >> 7;
      int bk = b * 4 + kvh;
#pragma unroll
      for (int m = 0; m < 4; m++)
#pragma unroll
        for (int n = 0; n < 2; n++) {
          int d = 32 * wc + 16 * n + ll;
          int tloc = 64 * wr + 16 * m + 4 * lg;
          u32 w0 = pk2(acc[m][n][0], acc[m][n][1]);
          u32 w1 = pk2(acc[m][n][2], acc[m][n][3]);
          int byte = (d * 256 + tloc * 2) ^ ((d & 7) << 4);
          *(uint2*)(lds + byte) = make_uint2(w0, w1);
        }
      __syncthreads();
      int tc = tid & 15, dbase = tid >> 4;
#pragma unroll
      for (int pass = 0; pass < 4; pass++) {
        int d = dbase + pass * 32;
        int byte = (d * 256 + tc * 16) ^ ((d & 7) << 4);
        uint4 v = *(const uint4*)(lds + byte);
        *(uint4*)(Vout + ((size_t)(bk * 128 + d)) * 2048 + t0g + tc * 8) = v;
      }
    }
  }
}

// ---------------- O-projection GEMM: 128x256 tile, 3-stage counted-vmcnt (r20-proven) ----------------
__global__ __launch_bounds__(512, 2) void k_gemm_o(
    const u16* __restrict__ A, const u16* __restrict__ BT, float* __restrict__ C) {
  __shared__ char lds[147456];
  const int K = 2048;
  int tid = threadIdx.x, w = tid >> 6, l = tid & 63, lg = l >> 4, ll = l & 15;
  int wr = w >> 2, wc = w & 3;
  int lid = blockIdx.y * 8 + blockIdx.x;
  int xcd = lid & 7, r = lid >> 3;
  int colg = xcd & 1, rowg = xcd >> 1;
  int bxt = colg * 4 + (r & 3);
  int bm0 = (rowg * 8 + (r >> 2)) * 128;
  int bn0 = bxt * 256;

  auto stage = [&](int si, int kt) {
    char* Sb = lds + si * 49152;
    int k0 = kt * 64;
#pragma unroll
    for (int i = 0; i < 2; i++) {
      int base = i * 512 + (w << 6);
      int c = base + l;
      int row = c >> 3, kc = (c & 7) ^ (row & 7);
      gll16(A + (size_t)(bm0 + row) * K + k0 + kc * 8, Sb + base * 16);
    }
#pragma unroll
    for (int i = 0; i < 4; i++) {
      int base = i * 512 + (w << 6);
      int c = base + l;
      int row = c >> 3, kc = (c & 7) ^ (row & 7);
      gll16(BT + (size_t)(bn0 + row) * K + k0 + kc * 8, Sb + 16384 + base * 16);
    }
  };

  f32x4 acc[4][4] = {};
  stage(0, 0); stage(1, 1);
  asm volatile("s_waitcnt vmcnt(6)" ::: "memory");
  __builtin_amdgcn_s_barrier();
  __builtin_amdgcn_sched_barrier(0);

  for (int kt = 0; kt < 32; ++kt) {
    int cs = kt % 3;
    if (kt + 2 < 32) stage((kt + 2) % 3, kt + 2);
    char* As = lds + cs * 49152;
    char* Bs = As + 16384;
    __builtin_amdgcn_s_setprio(1);
#pragma unroll
    for (int ks = 0; ks < 2; ks++) {
      bf16x8 af[4], bf[4];
#pragma unroll
      for (int m = 0; m < 4; m++) {
        int row = 64 * wr + 16 * m + ll;
        af[m] = *(const bf16x8*)(As + row * 128 + (((lg + 4 * ks) ^ (row & 7)) << 4));
      }
#pragma unroll
      for (int n = 0; n < 4; n++) {
        int row = 64 * wc + 16 * n + ll;
        bf[n] = *(const bf16x8*)(Bs + row * 128 + (((lg + 4 * ks) ^ (row & 7)) << 4));
      }
#pragma unroll
      for (int m = 0; m < 4; m++)
#pragma unroll
        for (int n = 0; n < 4; n++)
          acc[m][n] = __builtin_amdgcn_mfma_f32_16x16x32_bf16(af[m], bf[n], acc[m][n], 0, 0, 0);
    }
    __builtin_amdgcn_s_setprio(0);
    if (kt + 2 < 32) {
      asm volatile("s_waitcnt vmcnt(6)" ::: "memory");
    } else {
      asm volatile("s_waitcnt vmcnt(0)" ::: "memory");
    }
    __builtin_amdgcn_s_barrier();
    __builtin_amdgcn_sched_barrier(0);
  }

#pragma unroll
  for (int m = 0; m < 4; m++)
#pragma unroll
    for (int n = 0; n < 4; n++) {
      int row = bm0 + 64 * wr + 16 * m + 4 * lg;
      int col = bn0 + 64 * wc + 16 * n + ll;
      float* cp = C + (size_t)row * 2048 + col;
#pragma unroll
      for (int r2 = 0; r2 < 4; r2++) cp[(size_t)r2 * 2048] = acc[m][n][r2];
    }
}

// ---------------- causal GQA flash attention: 4-heads-share-K/V (r19/r23-proven optimum) ----------------
// 256 blocks x 512 thr (8 waves = 2/SIMD at 1 block/CU). fid&7 -> (b,kvh) XCD slice;
// within-block pairing {rank, 63-rank} of 32-row q-tiles -> uniform 33 KV-tiles/block.
// r24-r26 lessons: 32-rows/wave amplification variants all lose (imbalance / solo-tail /
// under-residency); counted-vmcnt regresses here (L2-resident loads, r22).
__global__ __launch_bounds__(512, 2) void k_attn(
    const u16* __restrict__ Q, const u16* __restrict__ Kb,
    const u16* __restrict__ Vt, u16* __restrict__ Y) {
  __shared__ char lds[81920];  // K0 16K | V0 16K | K1 16K | V1 16K | P 16K
  char* Ps = lds + 65536;
  int tid = threadIdx.x, w = tid >> 6, l = tid & 63, lg = l >> 4, ll = l & 15;
  int fid = blockIdx.x;
  int g = fid & 7, rank = fid >> 3;   // rank 0..31
  int b = g >> 2, kvh = g & 3;
  int h = kvh * 4 + (w & 3);          // head per wave
  int rgrp = w >> 2;                  // row-group within the 32-row tile
  const u16* Kbase = Kb + ((size_t)b * 2048) * 512 + kvh * 128;
  const u16* Vbase = Vt + ((size_t)(b * 4 + kvh) * 128) * 2048;

  const bf16x8 vones = {(short)0x3F80, (short)0x3F80, (short)0x3F80, (short)0x3F80,
                        (short)0x3F80, (short)0x3F80, (short)0x3F80, (short)0x3F80};

  auto stage = [&](int bi, int k0) {
    char* Kd = lds + (bi ? 32768 : 0);
    char* Vd = Kd + 16384;
#pragma unroll
    for (int i = 0; i < 2; i++) {
      int base = i * 512 + (w << 6);
      int c = base + l;
      int dst = base * 16;
      int krow = c >> 4, ksrc = (c & 15) ^ (krow & 7);   // K tile [64][128]
      gll16(Kbase + (size_t)(k0 + krow) * 512 + ksrc * 8, Kd + dst);
      int vd = c >> 3, vsrc = (c & 7) ^ (vd & 7);        // V tile [128][64]
      gll16(Vbase + (size_t)vd * 2048 + k0 + vsrc * 8, Vd + dst);
    }
  };

#pragma unroll 1
  for (int qi = 0; qi < 2; qi++) {
    int qt = qi ? (63 - rank) : rank;   // 32-row q-tile index
    int q0 = qt * 32;
    int nt = (qt >> 1) + 1;             // KV tiles of 64 covering [0, q0+32)
    bf16x8 qf[4];
    {
      int qrow = b * 2048 + q0 + rgrp * 16 + ll;
      const u16* qp = Q + (size_t)qrow * 2048 + h * 128;
#pragma unroll
      for (int ks = 0; ks < 4; ks++) qf[ks] = *(const bf16x8*)(qp + ks * 32 + lg * 8);
    }
    f32x4 o[8] = {};
    f32x4 lacc = {};

    stage(0, 0);
    asm volatile("s_waitcnt vmcnt(0)" ::: "memory");
    __syncthreads();

    int cur = 0;
    for (int it = 0; it < nt; ++it) {
      if (it + 1 < nt) stage(cur ^ 1, (it + 1) * 64);
      char* Ks = lds + (cur ? 32768 : 0);
      char* Vs = Ks + 16384;
      f32x4 s[4] = {};
      __builtin_amdgcn_s_setprio(1);
#pragma unroll
      for (int ks = 0; ks < 4; ks++) {
#pragma unroll
        for (int n = 0; n < 4; n++) {
          int row = 16 * n + ll;
          bf16x8 kf = *(const bf16x8*)(Ks + ((row * 256 + (lg + 4 * ks) * 16) ^ ((row & 7) << 4)));
          s[n] = __builtin_amdgcn_mfma_f32_16x16x32_bf16(qf[ks], kf, s[n], 0, 0, 0);
        }
      }
      __builtin_amdgcn_s_setprio(0);
      if (it == nt - 1) {  // diagonal tile: causal mask
        int k0 = it * 64;
#pragma unroll
        for (int n = 0; n < 4; n++) {
          int kk = k0 + 16 * n + ll;
#pragma unroll
          for (int r = 0; r < 4; r++) {
            int qq = q0 + rgrp * 16 + 4 * lg + r;
            if (kk > qq) s[n][r] = -1e30f;
          }
        }
      }
      // STATIC-normalizer softmax: P = exp2(s) directly (r15-proven)
#pragma unroll
      for (int r = 0; r < 4; r++) {
        int prow = 4 * lg + r;
#pragma unroll
        for (int n = 0; n < 4; n++) {
          float e = exp2f(s[n][r]);
          int byte = (w << 11) + ((prow * 128 + (16 * n + ll) * 2) ^ ((prow & 7) << 4));
          *(u16*)(Ps + byte) = f2bf_fast(e);
        }
      }
      // O += P V ; l += P 1 (row-sum on the MFMA pipe)
      __builtin_amdgcn_s_setprio(1);
#pragma unroll
      for (int ks = 0; ks < 2; ks++) {
        bf16x8 pf = *(const bf16x8*)(Ps + (w << 11) + ((ll * 128 + (lg + 4 * ks) * 16) ^ ((ll & 7) << 4)));
        lacc = __builtin_amdgcn_mfma_f32_16x16x32_bf16(pf, vones, lacc, 0, 0, 0);
#pragma unroll
        for (int n = 0; n < 8; n++) {
          int row = 16 * n + ll;
          bf16x8 vf = *(const bf16x8*)(Vs + ((row * 128 + (lg + 4 * ks) * 16) ^ ((row & 7) << 4)));
          o[n] = __builtin_amdgcn_mfma_f32_16x16x32_bf16(pf, vf, o[n], 0, 0, 0);
        }
      }
      __builtin_amdgcn_s_setprio(0);
      asm volatile("s_waitcnt vmcnt(0)" ::: "memory");
      __syncthreads();
      cur ^= 1;
    }
    // output
    float rl[4];
#pragma unroll
    for (int r = 0; r < 4; r++) rl[r] = 1.0f / lacc[r];
#pragma unroll
    for (int n = 0; n < 8; n++) {
      int col = h * 128 + 16 * n + ll;
#pragma unroll
      for (int r = 0; r < 4; r++) {
        int trow = b * 2048 + q0 + rgrp * 16 + 4 * lg + r;
        Y[(size_t)trow * 2048 + col] = f2bf_fast(o[n][r] * rl[r]);
      }
    }
  }
}

extern "C" void kernel_launch(void* const* d_in, const int* in_sizes, int n_in,
                              void* d_out, int out_size, void* d_ws, size_t ws_size,
                              hipStream_t stream) {
  const float* x   = (const float*)d_in[0];
  const float* fc  = (const float*)d_in[1];
  const float* fs  = (const float*)d_in[2];
  const float* wq  = (const float*)d_in[3];
  const float* wk  = (const float*)d_in[4];
  const float* wv  = (const float*)d_in[5];
  const float* wo  = (const float*)d_in[6];
  const float* qnw = (const float*)d_in[7];
  const float* knw = (const float*)d_in[8];
  float* out = (float*)d_out;

  const size_t MB = 1ull << 20;
  char* ws = (char*)d_ws;
  u16*    xb   = (u16*)(ws);             // 16 MB  x bf16
  u16*    wqt  = (u16*)(ws + 16 * MB);   //  8 MB  wq^T bf16 [2048][2048]
  u16*    wkvt = (u16*)(ws + 24 * MB);   //  4 MB  [wk^T;wv^T] bf16 [1024][2048]
  u16*    wot  = (u16*)(ws + 28 * MB);   //  8 MB  wo^T bf16
  u16*    Qb   = (u16*)(ws + 36 * MB);   // 16 MB  Q' bf16 (rms+rope, x log2e/sqrt(D))
  u16*    Kbq  = (u16*)(ws + 52 * MB);   //  4 MB  K' bf16 (rms+rope)
  u16*    Vtg  = (u16*)(ws + 56 * MB);   //  4 MB  V^T bf16 (b,kvh,d,t)
  u16*    Yb   = (u16*)(ws + 60 * MB);   // 16 MB  attn out bf16
  float2* fcs  = (float2*)(ws + 76 * MB);//  1 MB  fused (cos,sin) table

  hipLaunchKernelGGL(k_prep, dim3(6720), dim3(256), 0, stream,
                     x, xb, wq, wqt, wk, wv, wkvt, wo, wot, fc, fs, fcs);
  hipLaunchKernelGGL(k_gemm_qkv, dim3(512), dim3(512), 0, stream,
                     xb, wqt, wkvt, Qb, Kbq, Vtg, qnw, knw, fcs);
  hipLaunchKernelGGL(k_attn, dim3(256), dim3(512), 0, stream, Qb, Kbq, Vtg, Yb);
  hipLaunchKernelGGL(k_gemm_o, dim3(8, 32), dim3(512), 0, stream, Yb, wot, out);
}

// Round 28
// 186.087 us; speedup vs baseline: 1.0599x; 1.0031x over previous
//
#include <hip/hip_runtime.h>
#include <hip/hip_bf16.h>

using u16 = unsigned short;
using u32 = unsigned int;

typedef short bf16x8 __attribute__((ext_vector_type(8)));
typedef float f32x4 __attribute__((ext_vector_type(4)));

#define AS1 __attribute__((address_space(1)))
#define AS3 __attribute__((address_space(3)))

__device__ __forceinline__ void gll16(const void* g, void* l) {
  __builtin_amdgcn_global_load_lds((const AS1 u32*)g, (AS3 u32*)l, 16, 0, 0);
}

__device__ __forceinline__ u16 f2bf(float x) {  // round-to-nearest-even bf16
  u32 u = __builtin_bit_cast(u32, x);
  u32 r = (u + 0x7fffu + ((u >> 16) & 1u)) >> 16;
  return (u16)r;
}
__device__ __forceinline__ u32 pk2(float lo, float hi) {
  return (u32)f2bf(lo) | ((u32)f2bf(hi) << 16);
}
__device__ __forceinline__ u16 f2bf_fast(float x) {  // hw cvt (validated r5/r6)
  __hip_bfloat16 h = __float2bfloat16(x);
  return __builtin_bit_cast(u16, h);
}

// ---------------- merged prep: x cast + 4 weight transposes + fused cos/sin table ----------------
__device__ __forceinline__ void trans64(const float* __restrict__ in, u16* __restrict__ out,
                                        int R, int Cc, int bx, int by, float (*tl)[65]) {
  int c0 = bx * 64, r0 = by * 64, tid = threadIdx.x;
#pragma unroll
  for (int i = 0; i < 16; i++) {
    int idx = i * 256 + tid; int tr = idx >> 6, tc = idx & 63;
    tl[tr][tc] = in[(size_t)(r0 + tr) * Cc + c0 + tc];
  }
  __syncthreads();
#pragma unroll
  for (int i = 0; i < 16; i++) {
    int idx = i * 256 + tid; int tr = idx >> 6, tc = idx & 63;
    out[(size_t)(c0 + tr) * R + r0 + tc] = f2bf(tl[tc][tr]);
  }
}

__global__ void k_prep(const float* __restrict__ x, u16* __restrict__ xb,
                       const float* __restrict__ wq, u16* __restrict__ wqt,
                       const float* __restrict__ wk, const float* __restrict__ wv,
                       u16* __restrict__ wkvt,
                       const float* __restrict__ wo, u16* __restrict__ wot,
                       const float* __restrict__ fc, const float* __restrict__ fs,
                       float2* __restrict__ fcs) {
  __shared__ float tl[64][65];
  int gid = blockIdx.x;
  if (gid < 4096) {
    int i = gid * 256 + threadIdx.x;
    const float4* p = (const float4*)(x + (size_t)i * 8);
    float4 a = p[0], b = p[1];
    uint4 o;
    o.x = pk2(a.x, a.y); o.y = pk2(a.z, a.w);
    o.z = pk2(b.x, b.y); o.w = pk2(b.z, b.w);
    *(uint4*)(xb + (size_t)i * 8) = o;
  } else if (gid < 5120) {
    int t = gid - 4096; trans64(wq, wqt, 2048, 2048, t & 31, t >> 5, tl);
  } else if (gid < 5376) {
    int t = gid - 5120; trans64(wk, wkvt, 2048, 512, t & 7, t >> 3, tl);
  } else if (gid < 5632) {
    int t = gid - 5376; trans64(wv, wkvt + 512 * 2048, 2048, 512, t & 7, t >> 3, tl);
  } else if (gid < 6656) {
    int t = gid - 5632; trans64(wo, wot, 2048, 2048, t & 31, t >> 5, tl);
  } else {
    int base = (gid - 6656) * 2048 + threadIdx.x * 8;
#pragma unroll
    for (int j = 0; j < 8; j++) {
      int idx = base + j;
      fcs[idx] = make_float2(fc[idx], fs[idx]);
    }
  }
}

// ---------------- QKV GEMM: heterogeneous tiles (r21-proven) ----------------
__global__ __launch_bounds__(512, 2) void k_gemm_qkv(
    const u16* __restrict__ A, const u16* __restrict__ BT0, const u16* __restrict__ BT1,
    u16* __restrict__ Qout, u16* __restrict__ Kout, u16* __restrict__ Vout,
    const float* __restrict__ nwq, const float* __restrict__ nwk,
    const float2* __restrict__ fcs) {
  __shared__ char lds[147456];
  const int K = 2048;
  int tid = threadIdx.x, w = tid >> 6, l = tid & 63, lg = l >> 4, ll = l & 15;
  int bid = blockIdx.x;

  if (bid < 256) {
    // ---------- HEAVY: Q, BN=256, 3-stage counted-vmcnt ----------
    int wr = w >> 2, wc = w & 3;
    int xcd = bid & 7, r = bid >> 3;
    int colg = xcd & 1, rowg = xcd >> 1;
    int bxt = colg * 4 + (r & 3);
    int bm0 = (rowg * 8 + (r >> 2)) * 128;
    int bn0 = bxt * 256;

    auto stage = [&](int si, int kt) {
      char* Sb = lds + si * 49152;
      int k0 = kt * 64;
#pragma unroll
      for (int i = 0; i < 2; i++) {
        int base = i * 512 + (w << 6);
        int c = base + l;
        int row = c >> 3, kc = (c & 7) ^ (row & 7);
        gll16(A + (size_t)(bm0 + row) * K + k0 + kc * 8, Sb + base * 16);
      }
#pragma unroll
      for (int i = 0; i < 4; i++) {
        int base = i * 512 + (w << 6);
        int c = base + l;
        int row = c >> 3, kc = (c & 7) ^ (row & 7);
        gll16(BT0 + (size_t)(bn0 + row) * K + k0 + kc * 8, Sb + 16384 + base * 16);
      }
    };

    f32x4 acc[4][4] = {};
    stage(0, 0); stage(1, 1);
    asm volatile("s_waitcnt vmcnt(6)" ::: "memory");
    __builtin_amdgcn_s_barrier();
    __builtin_amdgcn_sched_barrier(0);

    for (int kt = 0; kt < 32; ++kt) {
      int cs = kt % 3;
      if (kt + 2 < 32) stage((kt + 2) % 3, kt + 2);
      char* As = lds + cs * 49152;
      char* Bs = As + 16384;
      __builtin_amdgcn_s_setprio(1);
#pragma unroll
      for (int ks = 0; ks < 2; ks++) {
        bf16x8 af[4], bf[4];
#pragma unroll
        for (int m = 0; m < 4; m++) {
          int row = 64 * wr + 16 * m + ll;
          af[m] = *(const bf16x8*)(As + row * 128 + (((lg + 4 * ks) ^ (row & 7)) << 4));
        }
#pragma unroll
        for (int n = 0; n < 4; n++) {
          int row = 64 * wc + 16 * n + ll;
          bf[n] = *(const bf16x8*)(Bs + row * 128 + (((lg + 4 * ks) ^ (row & 7)) << 4));
        }
#pragma unroll
        for (int m = 0; m < 4; m++)
#pragma unroll
          for (int n = 0; n < 4; n++)
            acc[m][n] = __builtin_amdgcn_mfma_f32_16x16x32_bf16(af[m], bf[n], acc[m][n], 0, 0, 0);
      }
      __builtin_amdgcn_s_setprio(0);
      if (kt + 2 < 32) {
        asm volatile("s_waitcnt vmcnt(6)" ::: "memory");
      } else {
        asm volatile("s_waitcnt vmcnt(0)" ::: "memory");
      }
      __builtin_amdgcn_s_barrier();
      __builtin_amdgcn_sched_barrier(0);
    }

    // --- Q epilogue: rmsnorm per 128-col head (wc pairs {0,1},{2,3}) + rope ---
    float* ssum = (float*)lds;
    float ps[4][4];
#pragma unroll
    for (int m = 0; m < 4; m++)
#pragma unroll
      for (int r2 = 0; r2 < 4; r2++) {
        float p = 0.f;
#pragma unroll
        for (int n = 0; n < 4; n++) p += acc[m][n][r2] * acc[m][n][r2];
#pragma unroll
        for (int msk = 1; msk < 16; msk <<= 1) p += __shfl_xor(p, msk);
        ps[m][r2] = p;
      }
    if (ll == 0) {
#pragma unroll
      for (int m = 0; m < 4; m++)
#pragma unroll
        for (int r2 = 0; r2 < 4; r2++)
          ssum[wr * 256 + (16 * m + 4 * lg + r2) * 4 + wc] = ps[m][r2];
    }
    __syncthreads();
    int pbase = (wc < 2) ? 0 : 2;
    float rs[4][4];
#pragma unroll
    for (int m = 0; m < 4; m++)
#pragma unroll
      for (int r2 = 0; r2 < 4; r2++) {
        int rowl = 16 * m + 4 * lg + r2;
        const float* sp = ssum + wr * 256 + rowl * 4;
        float tot = sp[pbase] + sp[pbase + 1];
        rs[m][r2] = rsqrtf(tot * (1.0f / 128.0f) + 1e-5f) * 0.12751744843f;
      }
#pragma unroll
    for (int m = 0; m < 4; m++)
#pragma unroll
      for (int n = 0; n < 4; n++) {
        int col = bn0 + 64 * wc + 16 * n + ll;
        int d = col & 127;
        float wgt = nwq[d];
        int i = d >> 1;
#pragma unroll
        for (int r2 = 0; r2 < 4; r2++) {
          int row = bm0 + 64 * wr + 16 * m + 4 * lg + r2;
          int t = row & 2047;
          float y = acc[m][n][r2] * rs[m][r2] * wgt;
          float p = __shfl_xor(y, 1);
          float2 cs2 = fcs[t * 64 + i];
          float o = (ll & 1) ? (p * cs2.y + y * cs2.x) : (y * cs2.x - p * cs2.y);
          Qout[(size_t)row * 2048 + col] = f2bf(o);
        }
      }
  } else {
    // ---------- LIGHT: K/V, BN=128, 4-stage counted-vmcnt ----------
    int wr = w >> 2, wc = w & 3;
    int lid = bid - 256;
    int xcd = lid & 7, r = lid >> 3;
    int colg = xcd & 1, rowg = xcd >> 1;
    int bxt = colg * 4 + (r & 3);
    int bm0 = (rowg * 8 + (r >> 2)) * 128;
    int bn0 = bxt * 128;
    bool kpath = (bn0 < 512);

    auto stage = [&](int si, int kt) {
      char* Sb = lds + si * 32768;
      int k0 = kt * 64;
#pragma unroll
      for (int i = 0; i < 2; i++) {
        int base = i * 512 + (w << 6);
        int c = base + l;
        int row = c >> 3, kc = (c & 7) ^ (row & 7);
        gll16(A + (size_t)(bm0 + row) * K + k0 + kc * 8, Sb + base * 16);
        gll16(BT1 + (size_t)(bn0 + row) * K + k0 + kc * 8, Sb + 16384 + base * 16);
      }
    };

    f32x4 acc[4][2] = {};
    stage(0, 0); stage(1, 1); stage(2, 2);
    asm volatile("s_waitcnt vmcnt(8)" ::: "memory");
    __builtin_amdgcn_s_barrier();
    __builtin_amdgcn_sched_barrier(0);

    for (int kt = 0; kt < 32; ++kt) {
      int cs = kt & 3;
      if (kt + 3 < 32) stage((kt + 3) & 3, kt + 3);
      char* As = lds + cs * 32768;
      char* Bs = As + 16384;
      __builtin_amdgcn_s_setprio(1);
#pragma unroll
      for (int ks = 0; ks < 2; ks++) {
        bf16x8 af[4], bf[2];
#pragma unroll
        for (int m = 0; m < 4; m++) {
          int row = 64 * wr + 16 * m + ll;
          af[m] = *(const bf16x8*)(As + row * 128 + (((lg + 4 * ks) ^ (row & 7)) << 4));
        }
#pragma unroll
        for (int n = 0; n < 2; n++) {
          int row = 32 * wc + 16 * n + ll;
          bf[n] = *(const bf16x8*)(Bs + row * 128 + (((lg + 4 * ks) ^ (row & 7)) << 4));
        }
#pragma unroll
        for (int m = 0; m < 4; m++)
#pragma unroll
          for (int n = 0; n < 2; n++)
            acc[m][n] = __builtin_amdgcn_mfma_f32_16x16x32_bf16(af[m], bf[n], acc[m][n], 0, 0, 0);
      }
      __builtin_amdgcn_s_setprio(0);
      if (kt <= 28) {
        asm volatile("s_waitcnt vmcnt(8)" ::: "memory");
      } else if (kt == 29) {
        asm volatile("s_waitcnt vmcnt(4)" ::: "memory");
      } else {
        asm volatile("s_waitcnt vmcnt(0)" ::: "memory");
      }
      __builtin_amdgcn_s_barrier();
      __builtin_amdgcn_sched_barrier(0);
    }

    if (kpath) {
      float* ssum = (float*)lds;
      float ps[4][4];
#pragma unroll
      for (int m = 0; m < 4; m++)
#pragma unroll
        for (int r2 = 0; r2 < 4; r2++) {
          float p = 0.f;
#pragma unroll
          for (int n = 0; n < 2; n++) p += acc[m][n][r2] * acc[m][n][r2];
#pragma unroll
          for (int msk = 1; msk < 16; msk <<= 1) p += __shfl_xor(p, msk);
          ps[m][r2] = p;
        }
      if (ll == 0) {
#pragma unroll
        for (int m = 0; m < 4; m++)
#pragma unroll
          for (int r2 = 0; r2 < 4; r2++)
            ssum[wr * 256 + (16 * m + 4 * lg + r2) * 4 + wc] = ps[m][r2];
      }
      __syncthreads();
      float rs[4][4];
#pragma unroll
      for (int m = 0; m < 4; m++)
#pragma unroll
        for (int r2 = 0; r2 < 4; r2++) {
          int rowl = 16 * m + 4 * lg + r2;
          const float* sp = ssum + wr * 256 + rowl * 4;
          float tot = sp[0] + sp[1] + sp[2] + sp[3];
          rs[m][r2] = rsqrtf(tot * (1.0f / 128.0f) + 1e-5f);
        }
#pragma unroll
      for (int m = 0; m < 4; m++)
#pragma unroll
        for (int n = 0; n < 2; n++) {
          int col = bn0 + 32 * wc + 16 * n + ll;
          int d = col & 127;
          float wgt = nwk[d];
          int i = d >> 1;
#pragma unroll
          for (int r2 = 0; r2 < 4; r2++) {
            int row = bm0 + 64 * wr + 16 * m + 4 * lg + r2;
            int t = row & 2047;
            float y = acc[m][n][r2] * rs[m][r2] * wgt;
            float p = __shfl_xor(y, 1);
            float2 cs2 = fcs[t * 64 + i];
            float o = (ll & 1) ? (p * cs2.y + y * cs2.x) : (y * cs2.x - p * cs2.y);
            Kout[(size_t)row * 512 + col] = f2bf(o);
          }
        }
    } else {
      int b = bm0 >> 11, t0g = bm0 & 2047;
      int kvh = (bn0 - 512) >> 7;
      int bk = b * 4 + kvh;
#pragma unroll
      for (int m = 0; m < 4; m++)
#pragma unroll
        for (int n = 0; n < 2; n++) {
          int d = 32 * wc + 16 * n + ll;
          int tloc = 64 * wr + 16 * m + 4 * lg;
          u32 w0 = pk2(acc[m][n][0], acc[m][n][1]);
          u32 w1 = pk2(acc[m][n][2], acc[m][n][3]);
          int byte = (d * 256 + tloc * 2) ^ ((d & 7) << 4);
          *(uint2*)(lds + byte) = make_uint2(w0, w1);
        }
      __syncthreads();
      int tc = tid & 15, dbase = tid >> 4;
#pragma unroll
      for (int pass = 0; pass < 4; pass++) {
        int d = dbase + pass * 32;
        int byte = (d * 256 + tc * 16) ^ ((d & 7) << 4);
        uint4 v = *(const uint4*)(lds + byte);
        *(uint4*)(Vout + ((size_t)(bk * 128 + d)) * 2048 + t0g + tc * 8) = v;
      }
    }
  }
}

// ---------------- O-projection GEMM: 128x256 tile, 3-stage counted-vmcnt (r20-proven) ----------------
__global__ __launch_bounds__(512, 2) void k_gemm_o(
    const u16* __restrict__ A, const u16* __restrict__ BT, float* __restrict__ C) {
  __shared__ char lds[147456];
  const int K = 2048;
  int tid = threadIdx.x, w = tid >> 6, l = tid & 63, lg = l >> 4, ll = l & 15;
  int wr = w >> 2, wc = w & 3;
  int lid = blockIdx.y * 8 + blockIdx.x;
  int xcd = lid & 7, r = lid >> 3;
  int colg = xcd & 1, rowg = xcd >> 1;
  int bxt = colg * 4 + (r & 3);
  int bm0 = (rowg * 8 + (r >> 2)) * 128;
  int bn0 = bxt * 256;

  auto stage = [&](int si, int kt) {
    char* Sb = lds + si * 49152;
    int k0 = kt * 64;
#pragma unroll
    for (int i = 0; i < 2; i++) {
      int base = i * 512 + (w << 6);
      int c = base + l;
      int row = c >> 3, kc = (c & 7) ^ (row & 7);
      gll16(A + (size_t)(bm0 + row) * K + k0 + kc * 8, Sb + base * 16);
    }
#pragma unroll
    for (int i = 0; i < 4; i++) {
      int base = i * 512 + (w << 6);
      int c = base + l;
      int row = c >> 3, kc = (c & 7) ^ (row & 7);
      gll16(BT + (size_t)(bn0 + row) * K + k0 + kc * 8, Sb + 16384 + base * 16);
    }
  };

  f32x4 acc[4][4] = {};
  stage(0, 0); stage(1, 1);
  asm volatile("s_waitcnt vmcnt(6)" ::: "memory");
  __builtin_amdgcn_s_barrier();
  __builtin_amdgcn_sched_barrier(0);

  for (int kt = 0; kt < 32; ++kt) {
    int cs = kt % 3;
    if (kt + 2 < 32) stage((kt + 2) % 3, kt + 2);
    char* As = lds + cs * 49152;
    char* Bs = As + 16384;
    __builtin_amdgcn_s_setprio(1);
#pragma unroll
    for (int ks = 0; ks < 2; ks++) {
      bf16x8 af[4], bf[4];
#pragma unroll
      for (int m = 0; m < 4; m++) {
        int row = 64 * wr + 16 * m + ll;
        af[m] = *(const bf16x8*)(As + row * 128 + (((lg + 4 * ks) ^ (row & 7)) << 4));
      }
#pragma unroll
      for (int n = 0; n < 4; n++) {
        int row = 64 * wc + 16 * n + ll;
        bf[n] = *(const bf16x8*)(Bs + row * 128 + (((lg + 4 * ks) ^ (row & 7)) << 4));
      }
#pragma unroll
      for (int m = 0; m < 4; m++)
#pragma unroll
        for (int n = 0; n < 4; n++)
          acc[m][n] = __builtin_amdgcn_mfma_f32_16x16x32_bf16(af[m], bf[n], acc[m][n], 0, 0, 0);
    }
    __builtin_amdgcn_s_setprio(0);
    if (kt + 2 < 32) {
      asm volatile("s_waitcnt vmcnt(6)" ::: "memory");
    } else {
      asm volatile("s_waitcnt vmcnt(0)" ::: "memory");
    }
    __builtin_amdgcn_s_barrier();
    __builtin_amdgcn_sched_barrier(0);
  }

#pragma unroll
  for (int m = 0; m < 4; m++)
#pragma unroll
    for (int n = 0; n < 4; n++) {
      int row = bm0 + 64 * wr + 16 * m + 4 * lg;
      int col = bn0 + 64 * wc + 16 * n + ll;
      float* cp = C + (size_t)row * 2048 + col;
#pragma unroll
      for (int r2 = 0; r2 < 4; r2++) cp[(size_t)r2 * 2048] = acc[m][n][r2];
    }
}

// ---------------- causal GQA flash attention (r23 body + conflict-free P swizzle, r28) ----------------
// P swizzle change: write pattern has prow=4lg+r with (r,n) instruction-constant, so the
// old ^((prow&7)<<4) spread lg over only 2 bank slots (bit-3 wraps the 32-bank cycle)
// -> 4-way write conflicts. New ^(((prow>>2)&3)<<5) XORs word-bits 3-4 with lg: low-5
// word bits become 8*(n^lg)+(ll>>1) = 32 distinct banks (conflict-free writes); pf reads
// (row=ll) alias 2-way = free (m136). Same f(row) at write & read sites; XOR<=96B stays
// inside each wave's 2KB P region. All else identical to the r23-proven optimum.
__global__ __launch_bounds__(512, 2) void k_attn(
    const u16* __restrict__ Q, const u16* __restrict__ Kb,
    const u16* __restrict__ Vt, u16* __restrict__ Y) {
  __shared__ char lds[81920];  // K0 16K | V0 16K | K1 16K | V1 16K | P 16K
  char* Ps = lds + 65536;
  int tid = threadIdx.x, w = tid >> 6, l = tid & 63, lg = l >> 4, ll = l & 15;
  int fid = blockIdx.x;
  int g = fid & 7, rank = fid >> 3;   // rank 0..31
  int b = g >> 2, kvh = g & 3;
  int h = kvh * 4 + (w & 3);          // head per wave
  int rgrp = w >> 2;                  // row-group within the 32-row tile
  const u16* Kbase = Kb + ((size_t)b * 2048) * 512 + kvh * 128;
  const u16* Vbase = Vt + ((size_t)(b * 4 + kvh) * 128) * 2048;

  const bf16x8 vones = {(short)0x3F80, (short)0x3F80, (short)0x3F80, (short)0x3F80,
                        (short)0x3F80, (short)0x3F80, (short)0x3F80, (short)0x3F80};

  auto stage = [&](int bi, int k0) {
    char* Kd = lds + (bi ? 32768 : 0);
    char* Vd = Kd + 16384;
#pragma unroll
    for (int i = 0; i < 2; i++) {
      int base = i * 512 + (w << 6);
      int c = base + l;
      int dst = base * 16;
      int krow = c >> 4, ksrc = (c & 15) ^ (krow & 7);   // K tile [64][128]
      gll16(Kbase + (size_t)(k0 + krow) * 512 + ksrc * 8, Kd + dst);
      int vd = c >> 3, vsrc = (c & 7) ^ (vd & 7);        // V tile [128][64]
      gll16(Vbase + (size_t)vd * 2048 + k0 + vsrc * 8, Vd + dst);
    }
  };

#pragma unroll 1
  for (int qi = 0; qi < 2; qi++) {
    int qt = qi ? (63 - rank) : rank;   // 32-row q-tile index
    int q0 = qt * 32;
    int nt = (qt >> 1) + 1;             // KV tiles of 64 covering [0, q0+32)
    bf16x8 qf[4];
    {
      int qrow = b * 2048 + q0 + rgrp * 16 + ll;
      const u16* qp = Q + (size_t)qrow * 2048 + h * 128;
#pragma unroll
      for (int ks = 0; ks < 4; ks++) qf[ks] = *(const bf16x8*)(qp + ks * 32 + lg * 8);
    }
    f32x4 o[8] = {};
    f32x4 lacc = {};

    stage(0, 0);
    asm volatile("s_waitcnt vmcnt(0)" ::: "memory");
    __syncthreads();

    int cur = 0;
    for (int it = 0; it < nt; ++it) {
      if (it + 1 < nt) stage(cur ^ 1, (it + 1) * 64);
      char* Ks = lds + (cur ? 32768 : 0);
      char* Vs = Ks + 16384;
      f32x4 s[4] = {};
      __builtin_amdgcn_s_setprio(1);
#pragma unroll
      for (int ks = 0; ks < 4; ks++) {
#pragma unroll
        for (int n = 0; n < 4; n++) {
          int row = 16 * n + ll;
          bf16x8 kf = *(const bf16x8*)(Ks + ((row * 256 + (lg + 4 * ks) * 16) ^ ((row & 7) << 4)));
          s[n] = __builtin_amdgcn_mfma_f32_16x16x32_bf16(qf[ks], kf, s[n], 0, 0, 0);
        }
      }
      __builtin_amdgcn_s_setprio(0);
      if (it == nt - 1) {  // diagonal tile: causal mask
        int k0 = it * 64;
#pragma unroll
        for (int n = 0; n < 4; n++) {
          int kk = k0 + 16 * n + ll;
#pragma unroll
          for (int r = 0; r < 4; r++) {
            int qq = q0 + rgrp * 16 + 4 * lg + r;
            if (kk > qq) s[n][r] = -1e30f;
          }
        }
      }
      // STATIC-normalizer softmax: P = exp2(s) directly (r15-proven)
      // P swizzle: conflict-free writes via ^(((prow>>2)&3)<<5) (r28 fix)
#pragma unroll
      for (int r = 0; r < 4; r++) {
        int prow = 4 * lg + r;
#pragma unroll
        for (int n = 0; n < 4; n++) {
          float e = exp2f(s[n][r]);
          int byte = (w << 11) + ((prow * 128 + (16 * n + ll) * 2) ^ (((prow >> 2) & 3) << 5));
          *(u16*)(Ps + byte) = f2bf_fast(e);
        }
      }
      // O += P V ; l += P 1 (row-sum on the MFMA pipe)
      __builtin_amdgcn_s_setprio(1);
#pragma unroll
      for (int ks = 0; ks < 2; ks++) {
        bf16x8 pf = *(const bf16x8*)(Ps + (w << 11) + ((ll * 128 + (lg + 4 * ks) * 16) ^ (((ll >> 2) & 3) << 5)));
        lacc = __builtin_amdgcn_mfma_f32_16x16x32_bf16(pf, vones, lacc, 0, 0, 0);
#pragma unroll
        for (int n = 0; n < 8; n++) {
          int row = 16 * n + ll;
          bf16x8 vf = *(const bf16x8*)(Vs + ((row * 128 + (lg + 4 * ks) * 16) ^ ((row & 7) << 4)));
          o[n] = __builtin_amdgcn_mfma_f32_16x16x32_bf16(pf, vf, o[n], 0, 0, 0);
        }
      }
      __builtin_amdgcn_s_setprio(0);
      asm volatile("s_waitcnt vmcnt(0)" ::: "memory");
      __syncthreads();
      cur ^= 1;
    }
    // output
    float rl[4];
#pragma unroll
    for (int r = 0; r < 4; r++) rl[r] = 1.0f / lacc[r];
#pragma unroll
    for (int n = 0; n < 8; n++) {
      int col = h * 128 + 16 * n + ll;
#pragma unroll
      for (int r = 0; r < 4; r++) {
        int trow = b * 2048 + q0 + rgrp * 16 + 4 * lg + r;
        Y[(size_t)trow * 2048 + col] = f2bf_fast(o[n][r] * rl[r]);
      }
    }
  }
}

extern "C" void kernel_launch(void* const* d_in, const int* in_sizes, int n_in,
                              void* d_out, int out_size, void* d_ws, size_t ws_size,
                              hipStream_t stream) {
  const float* x   = (const float*)d_in[0];
  const float* fc  = (const float*)d_in[1];
  const float* fs  = (const float*)d_in[2];
  const float* wq  = (const float*)d_in[3];
  const float* wk  = (const float*)d_in[4];
  const float* wv  = (const float*)d_in[5];
  const float* wo  = (const float*)d_in[6];
  const float* qnw = (const float*)d_in[7];
  const float* knw = (const float*)d_in[8];
  float* out = (float*)d_out;

  const size_t MB = 1ull << 20;
  char* ws = (char*)d_ws;
  u16*    xb   = (u16*)(ws);             // 16 MB  x bf16
  u16*    wqt  = (u16*)(ws + 16 * MB);   //  8 MB  wq^T bf16 [2048][2048]
  u16*    wkvt = (u16*)(ws + 24 * MB);   //  4 MB  [wk^T;wv^T] bf16 [1024][2048]
  u16*    wot  = (u16*)(ws + 28 * MB);   //  8 MB  wo^T bf16
  u16*    Qb   = (u16*)(ws + 36 * MB);   // 16 MB  Q' bf16 (rms+rope, x log2e/sqrt(D))
  u16*    Kbq  = (u16*)(ws + 52 * MB);   //  4 MB  K' bf16 (rms+rope)
  u16*    Vtg  = (u16*)(ws + 56 * MB);   //  4 MB  V^T bf16 (b,kvh,d,t)
  u16*    Yb   = (u16*)(ws + 60 * MB);   // 16 MB  attn out bf16
  float2* fcs  = (float2*)(ws + 76 * MB);//  1 MB  fused (cos,sin) table

  hipLaunchKernelGGL(k_prep, dim3(6720), dim3(256), 0, stream,
                     x, xb, wq, wqt, wk, wv, wkvt, wo, wot, fc, fs, fcs);
  hipLaunchKernelGGL(k_gemm_qkv, dim3(512), dim3(512), 0, stream,
                     xb, wqt, wkvt, Qb, Kbq, Vtg, qnw, knw, fcs);
  hipLaunchKernelGGL(k_attn, dim3(256), dim3(512), 0, stream, Qb, Kbq, Vtg, Yb);
  hipLaunchKernelGGL(k_gemm_o, dim3(8, 32), dim3(512), 0, stream, Yb, wot, out);
}